// Round 17
// baseline (434.179 us; speedup 1.0000x reference)
//
#include <hip/hip_runtime.h>
#include <hip/hip_bf16.h>

// Relative-position causal attention, B=4 H=16 Q=K=1024 D=64 (fp32 in/out).
// d_out = [output (BH*Q*D) | p_attn (BH*Q*K)] fp32.
// K0 k_vt: transpose V -> vt[bh][d][k] in ws (if ws_size allows).
// K1 k_scores: content scores (LDS-staged GEMM, counted vmcnt).
// K2 k_rel_pv: rel+exp -> e to P + fused PR (bv gather AFTER waitcnt: hidden
//              under compute); rowsum recip -> ws.
// K3 k_pv: Pn = e*recip in place (final p_attn), out += Pn@V (vt fast path).

#define BH 64
#define SQ 1024
#define SK 1024
#define DH 64
#define SCALE 0.125f

typedef __attribute__((ext_vector_type(4))) float f32x4;
typedef __attribute__((ext_vector_type(8))) unsigned short ushort8;
typedef __attribute__((ext_vector_type(8))) __bf16 bf16x8;

static __device__ inline unsigned short f2bf(float x) {
    unsigned u = __float_as_uint(x);
    unsigned r = u + 0x7FFFu + ((u >> 16) & 1u);
    return (unsigned short)(r >> 16);
}
static __device__ inline float bf2f(unsigned short s) {
    return __uint_as_float(((unsigned)s) << 16);
}

struct Frag2 { bf16x8 h, l; };

// Load 8 fp32, scale, split into hi/lo bf16 fragments (hi+lo == scaled value).
static __device__ inline Frag2 load_split(const float* __restrict__ p, float scale) {
    float4 x0 = *reinterpret_cast<const float4*>(p);
    float4 x1 = *reinterpret_cast<const float4*>(p + 4);
    float v[8] = {x0.x, x0.y, x0.z, x0.w, x1.x, x1.y, x1.z, x1.w};
    ushort8 uh, ul;
#pragma unroll
    for (int j = 0; j < 8; ++j) {
        float s = v[j] * scale;
        unsigned short h = f2bf(s);
        float r = s - bf2f(h);
        uh[j] = h;
        ul[j] = f2bf(r);
    }
    Frag2 f;
    f.h = __builtin_bit_cast(bf16x8, uh);
    f.l = __builtin_bit_cast(bf16x8, ul);
    return f;
}

static __device__ inline bf16x8 pack_bf8(float4 x0, float4 x1) {
    float v[8] = {x0.x, x0.y, x0.z, x0.w, x1.x, x1.y, x1.z, x1.w};
    ushort8 u;
#pragma unroll
    for (int j = 0; j < 8; ++j) u[j] = f2bf(v[j]);
    return __builtin_bit_cast(bf16x8, u);
}

static __device__ inline bf16x8 load_bf8(const float* __restrict__ p) {
    float4 x0 = *reinterpret_cast<const float4*>(p);
    float4 x1 = *reinterpret_cast<const float4*>(p + 4);
    return pack_bf8(x0, x1);
}

static __device__ inline bf16x8 load_bf8_strided(const float* __restrict__ p, int stride) {
    ushort8 u;
#pragma unroll
    for (int j = 0; j < 8; ++j) u[j] = f2bf(p[(size_t)j * stride]);
    return __builtin_bit_cast(bf16x8, u);
}

#define MFMA(a, b, c) __builtin_amdgcn_mfma_f32_16x16x32_bf16((a), (b), (c), 0, 0, 0)

// async global -> LDS, 16B per lane; lds dest is wave-uniform base + lane*16
#define GLLD(g, s)                                                              \
    __builtin_amdgcn_global_load_lds(                                           \
        (const __attribute__((address_space(1))) void*)(g),                     \
        (__attribute__((address_space(3))) void*)(s), 16, 0, 0)

// stage a 64x64 fp32 tile (rows at src0 + row*DH) into buf[b]; WAVE-PRIVATE:
// wave w stages rows [w*16, w*16+16) and later reads only those rows.
// source pre-swizzled (chunk ^= row&7) so linear LDS + swizzled reads match.
#define STAGE64(src0, b)                                                        \
    do {                                                                        \
        _Pragma("unroll")                                                       \
        for (int j_ = 0; j_ < 4; ++j_) {                                        \
            const int idx_ = w * 256 + j_ * 64 + l;                             \
            const int row_ = idx_ >> 4;                                         \
            const int g_ = (idx_ & 15) ^ (row_ & 7);                            \
            GLLD((src0) + (size_t)row_ * DH + g_ * 4,                           \
                 &buf[b][w * 256 + j_ * 64]);                                   \
        }                                                                       \
    } while (0)

#define WAITVN(n)                                                               \
    do {                                                                        \
        asm volatile("s_waitcnt vmcnt(" #n ")" ::: "memory");                   \
        __builtin_amdgcn_sched_barrier(0);                                      \
    } while (0)

// ---------------- K0: vt[bh][d][k] = V[bh][k][d]
__global__ __launch_bounds__(256) void k_vt(const float* __restrict__ V,
                                            float* __restrict__ vt) {
    __shared__ float tile[64][65];
    const int kt = blockIdx.x, bh = blockIdx.y;
    const int t = threadIdx.x;
    {
        const int kk = t >> 2, d0 = (t & 3) * 16;
        const float* src = V + ((size_t)bh * SK + kt * 64 + kk) * DH + d0;
#pragma unroll
        for (int j = 0; j < 4; ++j) {
            float4 v = *reinterpret_cast<const float4*>(src + j * 4);
            tile[d0 + j * 4 + 0][kk] = v.x;
            tile[d0 + j * 4 + 1][kk] = v.y;
            tile[d0 + j * 4 + 2][kk] = v.z;
            tile[d0 + j * 4 + 3][kk] = v.w;
        }
    }
    __syncthreads();
    {
        const int d = t >> 2, k0 = (t & 3) * 16;
        float* dst = vt + ((size_t)bh * DH + d) * SK + kt * 64 + k0;
#pragma unroll
        for (int j = 0; j < 4; ++j) {
            float4 v = {tile[d][k0 + j * 4 + 0], tile[d][k0 + j * 4 + 1],
                        tile[d][k0 + j * 4 + 2], tile[d][k0 + j * 4 + 3]};
            *reinterpret_cast<float4*>(dst + j * 4) = v;
        }
    }
}

// ---------------- K1: content scores Q@K^T * scale -> P (zeros above diag).
// 1-D grid: qt = bid>>6 (high bits), bh = bid&63 -> resident sets span sizes.
__global__ __launch_bounds__(256, 4) void k_scores(const float* __restrict__ qp,
                                                   const float* __restrict__ kp,
                                                   float* __restrict__ P) {
    __shared__ float4 buf[2][1024];
    const int bid = blockIdx.x;
    const int qt = bid >> 6;
    const int bh = bid & 63;
    const int tid = threadIdx.x;
    const int w = tid >> 6, l = tid & 63;
    const int lm = l & 15, lg = l >> 4;
    const int q0 = qt * 64;

    Frag2 qh0[4], qh1[4];  // pre-scaled by SCALE
#pragma unroll
    for (int nt = 0; nt < 4; ++nt) {
        const float* qrow = qp + ((size_t)bh * SQ + q0 + nt * 16 + lm) * DH + lg * 8;
        qh0[nt] = load_split(qrow, SCALE);
        qh1[nt] = load_split(qrow + 32, SCALE);
    }
    const float* kb = kp + (size_t)bh * SK * DH;
    const int nt_ = qt + 1;

    STAGE64(kb, 0);
#pragma unroll 1
    for (int t = 0; t < nt_; ++t) {
        if (t + 1 < nt_) {
            STAGE64(kb + (size_t)(t + 1) * 64 * DH, (t + 1) & 1);
            WAITVN(4);  // stage(t)+stores(t-1) landed; stage(t+1) in flight
        } else {
            WAITVN(0);
        }
        const float4* L = buf[t & 1];
        const int R = w * 16 + lm;
        const int sw = R & 7;
        float4 f0 = L[R * 16 + ((2 * lg) ^ sw)];
        float4 f1 = L[R * 16 + ((2 * lg + 1) ^ sw)];
        float4 f2 = L[R * 16 + ((8 + 2 * lg) ^ sw)];
        float4 f3 = L[R * 16 + ((9 + 2 * lg) ^ sw)];
        bf16x8 alo = pack_bf8(f0, f1);
        bf16x8 ahi = pack_bf8(f2, f3);
        const int kq = t * 64 + w * 16 + lg * 4;
        const bool diag = (t == qt);
#pragma unroll
        for (int nt = 0; nt < 4; ++nt) {
            f32x4 acc = {0.f, 0.f, 0.f, 0.f};
            acc = MFMA(alo, qh0[nt].h, acc);
            acc = MFMA(alo, qh0[nt].l, acc);
            acc = MFMA(ahi, qh1[nt].h, acc);
            acc = MFMA(ahi, qh1[nt].l, acc);
            const int qe = q0 + nt * 16 + lm;
            float ov[4];
#pragma unroll
            for (int r = 0; r < 4; ++r)
                ov[r] = (!diag || (kq + r <= qe)) ? acc[r] : 0.f;
            float4 o;
            o.x = ov[0]; o.y = ov[1]; o.z = ov[2]; o.w = ov[3];
            *reinterpret_cast<float4*>(&P[((size_t)bh * SQ + qe) * SK + kq]) = o;
        }
    }
    // zero-fill tiles fully above the diagonal
    const float4 z = {0.f, 0.f, 0.f, 0.f};
#pragma unroll 1
    for (int t = nt_; t < 16; ++t) {
        const int kq = t * 64 + w * 16 + lg * 4;
#pragma unroll
        for (int nt = 0; nt < 4; ++nt) {
            const int qe = q0 + nt * 16 + lm;
            *reinterpret_cast<float4*>(&P[((size_t)bh * SQ + qe) * SK + kq]) = z;
        }
    }
}

// ---------------- K2: rel+exp -> e to P, fused PR: out = (Σ e·bigr_v)/rowsum.
// 4-stripe balanced q map; bv gather moved AFTER waitcnt (hidden under compute).
__global__ __launch_bounds__(256) void k_rel_pv(const float* __restrict__ query,
                                                const float* __restrict__ bigr_k,
                                                const float* __restrict__ bigr_v,
                                                float* __restrict__ P,
                                                float* __restrict__ out,
                                                float* __restrict__ rs) {
    __shared__ float4 buf[2][1024];  // staging; reused for pr cross-wave reduce
    __shared__ float red[4][64];
    __shared__ float rsum[64];
    int q;
    {
        const int bid = blockIdx.x, c = bid & 255;
        switch (bid >> 8) {
            case 0:  q = 1023 - c; break;
            case 1:  q = c;        break;
            case 2:  q = 767 - c;  break;
            default: q = 256 + c;  break;
        }
    }
    const int KE = q + 1;
    const int nt_ = (KE + 63) >> 6;
    const int tid = threadIdx.x;
    const int w = tid >> 6, l = tid & 63;
    const int lm = l & 15, lg = l >> 4;

    Frag2 qh0[4], qh1[4];  // pre-scaled
    float* prow[4];
#pragma unroll
    for (int nt = 0; nt < 4; ++nt) {
        const int bh = nt * 16 + lm;
        const float* qrow = query + ((size_t)bh * SQ + q) * DH + lg * 8;
        qh0[nt] = load_split(qrow, SCALE);
        qh1[nt] = load_split(qrow + 32, SCALE);
        prow[nt] = P + ((size_t)bh * SQ + q) * SK;
    }
    const float* bk = bigr_k + (size_t)q * SK * DH;
    const float* bv = bigr_v + (size_t)q * SK * DH;
    float lsum[4] = {0.f, 0.f, 0.f, 0.f};
    f32x4 pr[4][4];  // [nt(bh group)][ntd(d group)]
#pragma unroll
    for (int a = 0; a < 4; ++a)
#pragma unroll
        for (int b = 0; b < 4; ++b) pr[a][b] = (f32x4){0.f, 0.f, 0.f, 0.f};

    STAGE64(bk, 0);
#pragma unroll 1
    for (int t = 0; t < nt_; ++t) {
        const int kq = t * 64 + w * 16 + lg * 4;
        float4 pc[4];
#pragma unroll
        for (int nt = 0; nt < 4; ++nt)
            pc[nt] = *reinterpret_cast<const float4*>(prow[nt] + kq);
        if (t + 1 < nt_) {
            STAGE64(bk + (size_t)(t + 1) * 64 * DH, (t + 1) & 1);
            WAITVN(4);  // stage(t)+pc+prev-bv+prev-stores landed; stage(t+1) in flight
        } else {
            WAITVN(0);
        }
        // bigr_v B-fragments: issued AFTER the wait -> latency hides under
        // QKT MFMA + exp below (compiler auto-waits before the PR MFMAs).
        bf16x8 bvf[4];
        {
            const int kbw = t * 64 + w * 16 + 4 * lg;
#pragma unroll
            for (int ntd = 0; ntd < 4; ++ntd) {
                ushort8 u;
#pragma unroll
                for (int j = 0; j < 4; ++j)
                    u[j] = f2bf(bv[(size_t)(kbw + j) * DH + ntd * 16 + lm]);
                u[4] = 0; u[5] = 0; u[6] = 0; u[7] = 0;
                bvf[ntd] = __builtin_bit_cast(bf16x8, u);
            }
        }
        const float4* L = buf[t & 1];
        const int R = w * 16 + lm;
        const int sw = R & 7;
        float4 f0 = L[R * 16 + ((2 * lg) ^ sw)];
        float4 f1 = L[R * 16 + ((2 * lg + 1) ^ sw)];
        float4 f2 = L[R * 16 + ((8 + 2 * lg) ^ sw)];
        float4 f3 = L[R * 16 + ((9 + 2 * lg) ^ sw)];
        bf16x8 alo = pack_bf8(f0, f1);
        bf16x8 ahi = pack_bf8(f2, f3);
#pragma unroll
        for (int nt = 0; nt < 4; ++nt) {
            f32x4 acc = {0.f, 0.f, 0.f, 0.f};
            acc = MFMA(alo, qh0[nt].h, acc);
            acc = MFMA(alo, qh0[nt].l, acc);
            acc = MFMA(ahi, qh1[nt].h, acc);
            acc = MFMA(ahi, qh1[nt].l, acc);
            const float4 c = pc[nt];
            float cv[4] = {c.x, c.y, c.z, c.w};
            float ov[4];
#pragma unroll
            for (int r = 0; r < 4; ++r) {
                float e = (kq + r < KE) ? __expf(cv[r] + acc[r]) : 0.f;
                ov[r] = e;
                lsum[nt] += e;
            }
            float4 o;
            o.x = ov[0]; o.y = ov[1]; o.z = ov[2]; o.w = ov[3];
            *reinterpret_cast<float4*>(prow[nt] + kq) = o;
            // PR accumulate: A = e (this lane's quad in slots 0..3), K=16 via
            // zeroed upper half; D[m=bh_in=lg*4+r][n=d_in=lm].
            ushort8 ua;
#pragma unroll
            for (int j = 0; j < 4; ++j) ua[j] = f2bf(ov[j]);
            ua[4] = 0; ua[5] = 0; ua[6] = 0; ua[7] = 0;
            bf16x8 af = __builtin_bit_cast(bf16x8, ua);
#pragma unroll
            for (int ntd = 0; ntd < 4; ++ntd)
                pr[nt][ntd] = MFMA(af, bvf[ntd], pr[nt][ntd]);
        }
    }

    // ---- row-sum reduce -> rsum (recip) in LDS + rs in global ----
#pragma unroll
    for (int nt = 0; nt < 4; ++nt) {
        float v = lsum[nt];
        v += __shfl_xor(v, 16);
        v += __shfl_xor(v, 32);
        if (l < 16) red[w][nt * 16 + l] = v;
    }
    __syncthreads();  // red ready; also: all staging reads of buf complete
    if (tid < 64) {
        float nr = 1.0f / (red[0][tid] + red[1][tid] + red[2][tid] + red[3][tid]);
        rsum[tid] = nr;
        rs[(size_t)q * 64 + tid] = nr;
    }
    // ---- pr cross-wave reduce in buf (32 KB = 2 halves of 4096 floats) ----
    float* prbuf = reinterpret_cast<float*>(&buf[0][0]);
    if (w < 2) {
        float* dst = prbuf + w * 4096;
#pragma unroll
        for (int nt = 0; nt < 4; ++nt)
#pragma unroll
            for (int ntd = 0; ntd < 4; ++ntd)
#pragma unroll
                for (int r = 0; r < 4; ++r)
                    dst[(nt * 16 + lg * 4 + r) * 64 + ntd * 16 + lm] = pr[nt][ntd][r];
    }
    __syncthreads();  // halves written (w0,w1); rsum ready
    if (w >= 2) {
        float* dst = prbuf + (w - 2) * 4096;
#pragma unroll
        for (int nt = 0; nt < 4; ++nt)
#pragma unroll
            for (int ntd = 0; ntd < 4; ++ntd)
#pragma unroll
                for (int r = 0; r < 4; ++r)
                    dst[(nt * 16 + lg * 4 + r) * 64 + ntd * 16 + lm] += pr[nt][ntd][r];
    }
    __syncthreads();
    // ---- final: out[bh][q][d] = (half0 + half1) * rsum[bh] ----
#pragma unroll
    for (int i = 0; i < 4; ++i) {
        const int f4i = tid + i * 256;  // 0..1023 float4s
        float4 a = reinterpret_cast<const float4*>(prbuf)[f4i];
        float4 b = reinterpret_cast<const float4*>(prbuf)[1024 + f4i];
        const int fl = f4i * 4;
        const int bh = fl >> 6, d = fl & 63;
        const float nr = rsum[bh];
        float4 o = {(a.x + b.x) * nr, (a.y + b.y) * nr,
                    (a.z + b.z) * nr, (a.w + b.w) * nr};
        *reinterpret_cast<float4*>(&out[((size_t)bh * SQ + q) * DH + d]) = o;
    }
}

// ---------------- K3: Pn = e*recip written in place (final p_attn);
// out += Pn @ V. 1-D grid: qt = bid>>6, bh = bid&63 (balanced residency).
// USE_VT: B-fragments from transposed vt[bh][d][k] (2 vector loads) else strided.
template <bool USE_VT>
__global__ __launch_bounds__(256) void k_pv(float* __restrict__ P,
                                            const float* __restrict__ V,
                                            const float* __restrict__ vt,
                                            const float* __restrict__ rs,
                                            float* __restrict__ out) {
    const int bid = blockIdx.x;
    const int qt = bid >> 6;
    const int bh = bid & 63;
    const int tid = threadIdx.x;
    const int w = tid >> 6, l = tid & 63;
    const int lm = l & 15, lg = l >> 4;
    const int q0 = qt * 64 + w * 16;

    const float wrecip = rs[(size_t)(q0 + lm) * 64 + bh];
    float orecip[4];
#pragma unroll
    for (int r = 0; r < 4; ++r)
        orecip[r] = rs[(size_t)(q0 + lg * 4 + r) * 64 + bh];

    f32x4 acc[4] = {{0.f,0.f,0.f,0.f},{0.f,0.f,0.f,0.f},{0.f,0.f,0.f,0.f},{0.f,0.f,0.f,0.f}};
    const int kend = q0 + 16;
    for (int k0 = 0; k0 < kend; k0 += 32) {
        float* arow = P + ((size_t)bh * SQ + q0 + lm) * SK + k0 + lg * 8;
        float4 x0 = *reinterpret_cast<const float4*>(arow);
        float4 x1 = *reinterpret_cast<const float4*>(arow + 4);
        float4 y0 = {x0.x * wrecip, x0.y * wrecip, x0.z * wrecip, x0.w * wrecip};
        float4 y1 = {x1.x * wrecip, x1.y * wrecip, x1.z * wrecip, x1.w * wrecip};
        *reinterpret_cast<float4*>(arow) = y0;       // final normalized p_attn
        *reinterpret_cast<float4*>(arow + 4) = y1;
        bf16x8 a = pack_bf8(x0, x1);                 // unnormalized e
#pragma unroll
        for (int nt = 0; nt < 4; ++nt) {
            bf16x8 b;
            if (USE_VT) {
                const float* bp = vt + ((size_t)bh * DH + nt * 16 + lm) * SK + k0 + lg * 8;
                b = load_bf8(bp);
            } else {
                const float* bcol = V + ((size_t)bh * SK + k0 + lg * 8) * DH + nt * 16 + lm;
                b = load_bf8_strided(bcol, DH);
            }
            acc[nt] = MFMA(a, b, acc[nt]);
        }
    }
#pragma unroll
    for (int nt = 0; nt < 4; ++nt)
#pragma unroll
        for (int r = 0; r < 4; ++r)
            out[((size_t)bh * SQ + q0 + lg * 4 + r) * DH + nt * 16 + lm] +=
                acc[nt][r] * orecip[r];
}

extern "C" void kernel_launch(void* const* d_in, const int* in_sizes, int n_in,
                              void* d_out, int out_size, void* d_ws, size_t ws_size,
                              hipStream_t stream) {
    const float* query  = (const float*)d_in[0];
    const float* key    = (const float*)d_in[1];
    const float* value  = (const float*)d_in[2];
    const float* bigr_k = (const float*)d_in[3];
    const float* bigr_v = (const float*)d_in[4];
    float* out = (float*)d_out;                       // BH*SQ*DH
    float* P   = out + (size_t)BH * SQ * DH;          // BH*SQ*SK
    float* rs  = (float*)d_ws;                        // [SQ][BH] recip = 256 KB
    float* vt  = rs + (size_t)SQ * 64;                // [BH][DH][SK] = 16 MB
    const bool use_vt =
        ws_size >= (size_t)SQ * 64 * 4 + (size_t)BH * DH * SK * 4;

    if (use_vt) k_vt<<<dim3(16, BH), 256, 0, stream>>>(value, vt);
    k_scores<<<dim3(1024), 256, 0, stream>>>(query, key, P);
    k_rel_pv<<<dim3(SQ), 256, 0, stream>>>(query, bigr_k, bigr_v, P, out, rs);
    if (use_vt)
        k_pv<true><<<dim3(1024), 256, 0, stream>>>(P, value, vt, rs, out);
    else
        k_pv<false><<<dim3(1024), 256, 0, stream>>>(P, value, vt, rs, out);
}

// Round 18
// 432.622 us; speedup vs baseline: 1.0036x; 1.0036x over previous
//
#include <hip/hip_runtime.h>
#include <hip/hip_bf16.h>

// Relative-position causal attention, B=4 H=16 Q=K=1024 D=64 (fp32 in/out).
// d_out = [output (BH*Q*D) | p_attn (BH*Q*K)] fp32.
// K1 k_scores: content scores (LDS-staged GEMM, counted vmcnt, 1-D grid).
// K2 k_rel_pv: k-SPLIT (grid 1024x2): rel+exp -> e to P + fused PR accumulated
//              into zero-init out via atomicAdd (2 addends -> deterministic);
//              per-half rowsums -> ws.  Max block 8 tiles -> refill, less tail.
// K3 k_pv: recip from ls halves; Pn = e*recip in place (final p_attn);
//          out = (out + PV) * recip.

#define BH 64
#define SQ 1024
#define SK 1024
#define DH 64
#define SCALE 0.125f

typedef __attribute__((ext_vector_type(4))) float f32x4;
typedef __attribute__((ext_vector_type(8))) unsigned short ushort8;
typedef __attribute__((ext_vector_type(8))) __bf16 bf16x8;

static __device__ inline unsigned short f2bf(float x) {
    unsigned u = __float_as_uint(x);
    unsigned r = u + 0x7FFFu + ((u >> 16) & 1u);
    return (unsigned short)(r >> 16);
}
static __device__ inline float bf2f(unsigned short s) {
    return __uint_as_float(((unsigned)s) << 16);
}

struct Frag2 { bf16x8 h, l; };

// Load 8 fp32, scale, split into hi/lo bf16 fragments (hi+lo == scaled value).
static __device__ inline Frag2 load_split(const float* __restrict__ p, float scale) {
    float4 x0 = *reinterpret_cast<const float4*>(p);
    float4 x1 = *reinterpret_cast<const float4*>(p + 4);
    float v[8] = {x0.x, x0.y, x0.z, x0.w, x1.x, x1.y, x1.z, x1.w};
    ushort8 uh, ul;
#pragma unroll
    for (int j = 0; j < 8; ++j) {
        float s = v[j] * scale;
        unsigned short h = f2bf(s);
        float r = s - bf2f(h);
        uh[j] = h;
        ul[j] = f2bf(r);
    }
    Frag2 f;
    f.h = __builtin_bit_cast(bf16x8, uh);
    f.l = __builtin_bit_cast(bf16x8, ul);
    return f;
}

static __device__ inline bf16x8 pack_bf8(float4 x0, float4 x1) {
    float v[8] = {x0.x, x0.y, x0.z, x0.w, x1.x, x1.y, x1.z, x1.w};
    ushort8 u;
#pragma unroll
    for (int j = 0; j < 8; ++j) u[j] = f2bf(v[j]);
    return __builtin_bit_cast(bf16x8, u);
}

static __device__ inline bf16x8 load_bf8(const float* __restrict__ p) {
    float4 x0 = *reinterpret_cast<const float4*>(p);
    float4 x1 = *reinterpret_cast<const float4*>(p + 4);
    return pack_bf8(x0, x1);
}

static __device__ inline bf16x8 load_bf8_strided(const float* __restrict__ p, int stride) {
    ushort8 u;
#pragma unroll
    for (int j = 0; j < 8; ++j) u[j] = f2bf(p[(size_t)j * stride]);
    return __builtin_bit_cast(bf16x8, u);
}

#define MFMA(a, b, c) __builtin_amdgcn_mfma_f32_16x16x32_bf16((a), (b), (c), 0, 0, 0)

// async global -> LDS, 16B per lane; lds dest is wave-uniform base + lane*16
#define GLLD(g, s)                                                              \
    __builtin_amdgcn_global_load_lds(                                           \
        (const __attribute__((address_space(1))) void*)(g),                     \
        (__attribute__((address_space(3))) void*)(s), 16, 0, 0)

// stage a 64x64 fp32 tile (rows at src0 + row*DH) into buf[b]; WAVE-PRIVATE:
// wave w stages rows [w*16, w*16+16) and later reads only those rows.
// source pre-swizzled (chunk ^= row&7) so linear LDS + swizzled reads match.
#define STAGE64(src0, b)                                                        \
    do {                                                                        \
        _Pragma("unroll")                                                       \
        for (int j_ = 0; j_ < 4; ++j_) {                                        \
            const int idx_ = w * 256 + j_ * 64 + l;                             \
            const int row_ = idx_ >> 4;                                         \
            const int g_ = (idx_ & 15) ^ (row_ & 7);                            \
            GLLD((src0) + (size_t)row_ * DH + g_ * 4,                           \
                 &buf[b][w * 256 + j_ * 64]);                                   \
        }                                                                       \
    } while (0)

#define WAITVN(n)                                                               \
    do {                                                                        \
        asm volatile("s_waitcnt vmcnt(" #n ")" ::: "memory");                   \
        __builtin_amdgcn_sched_barrier(0);                                      \
    } while (0)

// ---------------- K1: content scores Q@K^T * scale -> P (zeros above diag).
// 1-D grid: qt = bid>>6 (high bits), bh = bid&63 -> resident sets span sizes.
__global__ __launch_bounds__(256, 4) void k_scores(const float* __restrict__ qp,
                                                   const float* __restrict__ kp,
                                                   float* __restrict__ P) {
    __shared__ float4 buf[2][1024];
    const int bid = blockIdx.x;
    const int qt = bid >> 6;
    const int bh = bid & 63;
    const int tid = threadIdx.x;
    const int w = tid >> 6, l = tid & 63;
    const int lm = l & 15, lg = l >> 4;
    const int q0 = qt * 64;

    Frag2 qh0[4], qh1[4];  // pre-scaled by SCALE
#pragma unroll
    for (int nt = 0; nt < 4; ++nt) {
        const float* qrow = qp + ((size_t)bh * SQ + q0 + nt * 16 + lm) * DH + lg * 8;
        qh0[nt] = load_split(qrow, SCALE);
        qh1[nt] = load_split(qrow + 32, SCALE);
    }
    const float* kb = kp + (size_t)bh * SK * DH;
    const int nt_ = qt + 1;

    STAGE64(kb, 0);
#pragma unroll 1
    for (int t = 0; t < nt_; ++t) {
        if (t + 1 < nt_) {
            STAGE64(kb + (size_t)(t + 1) * 64 * DH, (t + 1) & 1);
            WAITVN(4);  // stage(t)+stores(t-1) landed; stage(t+1) in flight
        } else {
            WAITVN(0);
        }
        const float4* L = buf[t & 1];
        const int R = w * 16 + lm;
        const int sw = R & 7;
        float4 f0 = L[R * 16 + ((2 * lg) ^ sw)];
        float4 f1 = L[R * 16 + ((2 * lg + 1) ^ sw)];
        float4 f2 = L[R * 16 + ((8 + 2 * lg) ^ sw)];
        float4 f3 = L[R * 16 + ((9 + 2 * lg) ^ sw)];
        bf16x8 alo = pack_bf8(f0, f1);
        bf16x8 ahi = pack_bf8(f2, f3);
        const int kq = t * 64 + w * 16 + lg * 4;
        const bool diag = (t == qt);
#pragma unroll
        for (int nt = 0; nt < 4; ++nt) {
            f32x4 acc = {0.f, 0.f, 0.f, 0.f};
            acc = MFMA(alo, qh0[nt].h, acc);
            acc = MFMA(alo, qh0[nt].l, acc);
            acc = MFMA(ahi, qh1[nt].h, acc);
            acc = MFMA(ahi, qh1[nt].l, acc);
            const int qe = q0 + nt * 16 + lm;
            float ov[4];
#pragma unroll
            for (int r = 0; r < 4; ++r)
                ov[r] = (!diag || (kq + r <= qe)) ? acc[r] : 0.f;
            float4 o;
            o.x = ov[0]; o.y = ov[1]; o.z = ov[2]; o.w = ov[3];
            *reinterpret_cast<float4*>(&P[((size_t)bh * SQ + qe) * SK + kq]) = o;
        }
    }
    // zero-fill tiles fully above the diagonal
    const float4 z = {0.f, 0.f, 0.f, 0.f};
#pragma unroll 1
    for (int t = nt_; t < 16; ++t) {
        const int kq = t * 64 + w * 16 + lg * 4;
#pragma unroll
        for (int nt = 0; nt < 4; ++nt) {
            const int qe = q0 + nt * 16 + lm;
            *reinterpret_cast<float4*>(&P[((size_t)bh * SQ + qe) * SK + kq]) = z;
        }
    }
}

// ---------------- K2: k-split rel+exp+PR. Grid (1024 q-map, 2 halves).
// Half h owns tiles [ceil(nt/2)*h, ...); PR accumulated into out via atomicAdd
// (out zero-memset; exactly 2 addends per element -> deterministic).
__global__ __launch_bounds__(256) void k_rel_pv(const float* __restrict__ query,
                                                const float* __restrict__ bigr_k,
                                                const float* __restrict__ bigr_v,
                                                float* __restrict__ P,
                                                float* __restrict__ out,
                                                float* __restrict__ ls) {
    __shared__ float4 buf[2][1024];  // staging; reused for pr cross-wave reduce
    __shared__ float red[4][64];
    int q;
    {
        const int bid = blockIdx.x, c = bid & 255;
        switch (bid >> 8) {
            case 0:  q = 1023 - c; break;
            case 1:  q = c;        break;
            case 2:  q = 767 - c;  break;
            default: q = 256 + c;  break;
        }
    }
    const int h = blockIdx.y;
    const int KE = q + 1;
    const int nt_ = (KE + 63) >> 6;
    const int tA = h ? ((nt_ + 1) >> 1) : 0;
    const int tB = h ? nt_ : ((nt_ + 1) >> 1);
    const int tid = threadIdx.x;
    const int w = tid >> 6, l = tid & 63;
    const int lm = l & 15, lg = l >> 4;
    float* lsq = ls + ((size_t)q * 2 + h) * 64;
    if (tA >= tB) {  // empty half
        if (tid < 64) lsq[tid] = 0.f;
        return;
    }

    Frag2 qh0[4], qh1[4];  // pre-scaled
    float* prow[4];
#pragma unroll
    for (int nt = 0; nt < 4; ++nt) {
        const int bh = nt * 16 + lm;
        const float* qrow = query + ((size_t)bh * SQ + q) * DH + lg * 8;
        qh0[nt] = load_split(qrow, SCALE);
        qh1[nt] = load_split(qrow + 32, SCALE);
        prow[nt] = P + ((size_t)bh * SQ + q) * SK;
    }
    const float* bk = bigr_k + (size_t)q * SK * DH;
    const float* bv = bigr_v + (size_t)q * SK * DH;
    float lsum[4] = {0.f, 0.f, 0.f, 0.f};
    f32x4 pr[4][4];  // [nt(bh group)][ntd(d group)]
#pragma unroll
    for (int a = 0; a < 4; ++a)
#pragma unroll
        for (int b = 0; b < 4; ++b) pr[a][b] = (f32x4){0.f, 0.f, 0.f, 0.f};

    STAGE64(bk + (size_t)tA * 64 * DH, tA & 1);
#pragma unroll 1
    for (int t = tA; t < tB; ++t) {
        const int kq = t * 64 + w * 16 + lg * 4;
        float4 pc[4];
#pragma unroll
        for (int nt = 0; nt < 4; ++nt)
            pc[nt] = *reinterpret_cast<const float4*>(prow[nt] + kq);
        // bigr_v B-fragments for this wave's 16-k stripe (consumed this iter)
        bf16x8 bvf[4];
        {
            const int kbw = t * 64 + w * 16 + 4 * lg;
#pragma unroll
            for (int ntd = 0; ntd < 4; ++ntd) {
                ushort8 u;
#pragma unroll
                for (int j = 0; j < 4; ++j)
                    u[j] = f2bf(bv[(size_t)(kbw + j) * DH + ntd * 16 + lm]);
                u[4] = 0; u[5] = 0; u[6] = 0; u[7] = 0;
                bvf[ntd] = __builtin_bit_cast(bf16x8, u);
            }
        }
        if (t + 1 < tB) {
            STAGE64(bk + (size_t)(t + 1) * 64 * DH, (t + 1) & 1);
            WAITVN(4);  // stage(t)+pc+bv+prev-stores landed; stage(t+1) in flight
        } else {
            WAITVN(0);
        }
        const float4* L = buf[t & 1];
        const int R = w * 16 + lm;
        const int sw = R & 7;
        float4 f0 = L[R * 16 + ((2 * lg) ^ sw)];
        float4 f1 = L[R * 16 + ((2 * lg + 1) ^ sw)];
        float4 f2 = L[R * 16 + ((8 + 2 * lg) ^ sw)];
        float4 f3 = L[R * 16 + ((9 + 2 * lg) ^ sw)];
        bf16x8 alo = pack_bf8(f0, f1);
        bf16x8 ahi = pack_bf8(f2, f3);
#pragma unroll
        for (int nt = 0; nt < 4; ++nt) {
            f32x4 acc = {0.f, 0.f, 0.f, 0.f};
            acc = MFMA(alo, qh0[nt].h, acc);
            acc = MFMA(alo, qh0[nt].l, acc);
            acc = MFMA(ahi, qh1[nt].h, acc);
            acc = MFMA(ahi, qh1[nt].l, acc);
            const float4 c = pc[nt];
            float cv[4] = {c.x, c.y, c.z, c.w};
            float ov[4];
#pragma unroll
            for (int r = 0; r < 4; ++r) {
                float e = (kq + r < KE) ? __expf(cv[r] + acc[r]) : 0.f;
                ov[r] = e;
                lsum[nt] += e;
            }
            float4 o;
            o.x = ov[0]; o.y = ov[1]; o.z = ov[2]; o.w = ov[3];
            *reinterpret_cast<float4*>(prow[nt] + kq) = o;
            // PR accumulate: A = e quad in slots 0..3, K=16 via zeroed upper half
            ushort8 ua;
#pragma unroll
            for (int j = 0; j < 4; ++j) ua[j] = f2bf(ov[j]);
            ua[4] = 0; ua[5] = 0; ua[6] = 0; ua[7] = 0;
            bf16x8 af = __builtin_bit_cast(bf16x8, ua);
#pragma unroll
            for (int ntd = 0; ntd < 4; ++ntd)
                pr[nt][ntd] = MFMA(af, bvf[ntd], pr[nt][ntd]);
        }
    }

    // ---- per-half row sums -> ls[q][h][bh] ----
#pragma unroll
    for (int nt = 0; nt < 4; ++nt) {
        float v = lsum[nt];
        v += __shfl_xor(v, 16);
        v += __shfl_xor(v, 32);
        if (l < 16) red[w][nt * 16 + l] = v;
    }
    __syncthreads();  // red ready; all staging reads of buf complete
    if (tid < 64)
        lsq[tid] = red[0][tid] + red[1][tid] + red[2][tid] + red[3][tid];
    // ---- pr cross-wave reduce in buf (32 KB = 2 halves of 4096 floats) ----
    float* prbuf = reinterpret_cast<float*>(&buf[0][0]);
    if (w < 2) {
        float* dst = prbuf + w * 4096;
#pragma unroll
        for (int nt = 0; nt < 4; ++nt)
#pragma unroll
            for (int ntd = 0; ntd < 4; ++ntd)
#pragma unroll
                for (int r = 0; r < 4; ++r)
                    dst[(nt * 16 + lg * 4 + r) * 64 + ntd * 16 + lm] = pr[nt][ntd][r];
    }
    __syncthreads();
    if (w >= 2) {
        float* dst = prbuf + (w - 2) * 4096;
#pragma unroll
        for (int nt = 0; nt < 4; ++nt)
#pragma unroll
            for (int ntd = 0; ntd < 4; ++ntd)
#pragma unroll
                for (int r = 0; r < 4; ++r)
                    dst[(nt * 16 + lg * 4 + r) * 64 + ntd * 16 + lm] += pr[nt][ntd][r];
    }
    __syncthreads();
    // ---- atomic accumulate unnormalized PR into out ----
#pragma unroll
    for (int i = 0; i < 4; ++i) {
        const int f4i = tid + i * 256;  // 0..1023 float4s
        float4 a = reinterpret_cast<const float4*>(prbuf)[f4i];
        float4 b = reinterpret_cast<const float4*>(prbuf)[1024 + f4i];
        const int fl = f4i * 4;
        const int bh = fl >> 6, d = fl & 63;
        float* dst = &out[((size_t)bh * SQ + q) * DH + d];
        atomicAdd(dst + 0, a.x + b.x);
        atomicAdd(dst + 1, a.y + b.y);
        atomicAdd(dst + 2, a.z + b.z);
        atomicAdd(dst + 3, a.w + b.w);
    }
}

// ---------------- K3: recip from ls halves; Pn = e*recip in place (final
// p_attn); out = (out_PR + PV_unnorm) * recip. 1-D grid qt=bid>>6, bh=bid&63.
__global__ __launch_bounds__(256) void k_pv(float* __restrict__ P,
                                            const float* __restrict__ V,
                                            const float* __restrict__ ls,
                                            float* __restrict__ out) {
    const int bid = blockIdx.x;
    const int qt = bid >> 6;
    const int bh = bid & 63;
    const int tid = threadIdx.x;
    const int w = tid >> 6, l = tid & 63;
    const int lm = l & 15, lg = l >> 4;
    const int q0 = qt * 64 + w * 16;

    const float wrecip =
        1.0f / (ls[(size_t)(q0 + lm) * 128 + bh] +
                ls[(size_t)(q0 + lm) * 128 + 64 + bh]);
    float orecip[4];
#pragma unroll
    for (int r = 0; r < 4; ++r)
        orecip[r] = 1.0f / (ls[(size_t)(q0 + lg * 4 + r) * 128 + bh] +
                            ls[(size_t)(q0 + lg * 4 + r) * 128 + 64 + bh]);

    f32x4 acc[4] = {{0.f,0.f,0.f,0.f},{0.f,0.f,0.f,0.f},{0.f,0.f,0.f,0.f},{0.f,0.f,0.f,0.f}};
    const int kend = q0 + 16;
    for (int k0 = 0; k0 < kend; k0 += 32) {
        float* arow = P + ((size_t)bh * SQ + q0 + lm) * SK + k0 + lg * 8;
        float4 x0 = *reinterpret_cast<const float4*>(arow);
        float4 x1 = *reinterpret_cast<const float4*>(arow + 4);
        float4 y0 = {x0.x * wrecip, x0.y * wrecip, x0.z * wrecip, x0.w * wrecip};
        float4 y1 = {x1.x * wrecip, x1.y * wrecip, x1.z * wrecip, x1.w * wrecip};
        *reinterpret_cast<float4*>(arow) = y0;       // final normalized p_attn
        *reinterpret_cast<float4*>(arow + 4) = y1;
        bf16x8 a = pack_bf8(x0, x1);                 // unnormalized e
#pragma unroll
        for (int nt = 0; nt < 4; ++nt) {
            const float* bcol = V + ((size_t)bh * SK + k0 + lg * 8) * DH + nt * 16 + lm;
            bf16x8 b = load_bf8_strided(bcol, DH);
            acc[nt] = MFMA(a, b, acc[nt]);
        }
    }
#pragma unroll
    for (int nt = 0; nt < 4; ++nt)
#pragma unroll
        for (int r = 0; r < 4; ++r) {
            float* op = &out[((size_t)bh * SQ + q0 + lg * 4 + r) * DH + nt * 16 + lm];
            *op = (*op + acc[nt][r]) * orecip[r];
        }
}

extern "C" void kernel_launch(void* const* d_in, const int* in_sizes, int n_in,
                              void* d_out, int out_size, void* d_ws, size_t ws_size,
                              hipStream_t stream) {
    const float* query  = (const float*)d_in[0];
    const float* key    = (const float*)d_in[1];
    const float* value  = (const float*)d_in[2];
    const float* bigr_k = (const float*)d_in[3];
    const float* bigr_v = (const float*)d_in[4];
    float* out = (float*)d_out;                       // BH*SQ*DH
    float* P   = out + (size_t)BH * SQ * DH;          // BH*SQ*SK
    float* ls  = (float*)d_ws;                        // [SQ][2][BH] = 512 KB

    hipMemsetAsync(out, 0, (size_t)BH * SQ * DH * sizeof(float), stream);
    k_scores<<<dim3(1024), 256, 0, stream>>>(query, key, P);
    k_rel_pv<<<dim3(1024, 2), 256, 0, stream>>>(query, bigr_k, bigr_v, P, out, ls);
    k_pv<<<dim3(1024), 256, 0, stream>>>(P, value, ls, out);
}

// Round 19
// 406.605 us; speedup vs baseline: 1.0678x; 1.0640x over previous
//
#include <hip/hip_runtime.h>
#include <hip/hip_bf16.h>

// Relative-position causal attention, B=4 H=16 Q=K=1024 D=64 (fp32 in/out).
// d_out = [output (BH*Q*D) | p_attn (BH*Q*K)] fp32.
// Measured-best build (R16, 403 us):
// K1 k_scores: content scores (LDS-staged GEMM, counted vmcnt, 1-D grid,
//              qt in high bits for balanced residency).
// K2 k_rel_pv: rel+exp -> e to P + fused PR (out = (sum e*bigr_v)/rowsum) via
//              C-layout==A-layout identity, half-K MFMA; 4-stripe balanced q map;
//              rowsum recip -> ws.
// K3 k_pv: Pn = e*recip in place (final p_attn), out += Pn@V (strided V loads,
//          L2/L3-resident; 1-D grid).

#define BH 64
#define SQ 1024
#define SK 1024
#define DH 64
#define SCALE 0.125f

typedef __attribute__((ext_vector_type(4))) float f32x4;
typedef __attribute__((ext_vector_type(8))) unsigned short ushort8;
typedef __attribute__((ext_vector_type(8))) __bf16 bf16x8;

static __device__ inline unsigned short f2bf(float x) {
    unsigned u = __float_as_uint(x);
    unsigned r = u + 0x7FFFu + ((u >> 16) & 1u);
    return (unsigned short)(r >> 16);
}
static __device__ inline float bf2f(unsigned short s) {
    return __uint_as_float(((unsigned)s) << 16);
}

struct Frag2 { bf16x8 h, l; };

// Load 8 fp32, scale, split into hi/lo bf16 fragments (hi+lo == scaled value).
static __device__ inline Frag2 load_split(const float* __restrict__ p, float scale) {
    float4 x0 = *reinterpret_cast<const float4*>(p);
    float4 x1 = *reinterpret_cast<const float4*>(p + 4);
    float v[8] = {x0.x, x0.y, x0.z, x0.w, x1.x, x1.y, x1.z, x1.w};
    ushort8 uh, ul;
#pragma unroll
    for (int j = 0; j < 8; ++j) {
        float s = v[j] * scale;
        unsigned short h = f2bf(s);
        float r = s - bf2f(h);
        uh[j] = h;
        ul[j] = f2bf(r);
    }
    Frag2 f;
    f.h = __builtin_bit_cast(bf16x8, uh);
    f.l = __builtin_bit_cast(bf16x8, ul);
    return f;
}

static __device__ inline bf16x8 pack_bf8(float4 x0, float4 x1) {
    float v[8] = {x0.x, x0.y, x0.z, x0.w, x1.x, x1.y, x1.z, x1.w};
    ushort8 u;
#pragma unroll
    for (int j = 0; j < 8; ++j) u[j] = f2bf(v[j]);
    return __builtin_bit_cast(bf16x8, u);
}

static __device__ inline bf16x8 load_bf8(const float* __restrict__ p) {
    float4 x0 = *reinterpret_cast<const float4*>(p);
    float4 x1 = *reinterpret_cast<const float4*>(p + 4);
    return pack_bf8(x0, x1);
}

static __device__ inline bf16x8 load_bf8_strided(const float* __restrict__ p, int stride) {
    ushort8 u;
#pragma unroll
    for (int j = 0; j < 8; ++j) u[j] = f2bf(p[(size_t)j * stride]);
    return __builtin_bit_cast(bf16x8, u);
}

#define MFMA(a, b, c) __builtin_amdgcn_mfma_f32_16x16x32_bf16((a), (b), (c), 0, 0, 0)

// async global -> LDS, 16B per lane; lds dest is wave-uniform base + lane*16
#define GLLD(g, s)                                                              \
    __builtin_amdgcn_global_load_lds(                                           \
        (const __attribute__((address_space(1))) void*)(g),                     \
        (__attribute__((address_space(3))) void*)(s), 16, 0, 0)

// stage a 64x64 fp32 tile (rows at src0 + row*DH) into buf[b]; WAVE-PRIVATE:
// wave w stages rows [w*16, w*16+16) and later reads only those rows.
// source pre-swizzled (chunk ^= row&7) so linear LDS + swizzled reads match.
#define STAGE64(src0, b)                                                        \
    do {                                                                        \
        _Pragma("unroll")                                                       \
        for (int j_ = 0; j_ < 4; ++j_) {                                        \
            const int idx_ = w * 256 + j_ * 64 + l;                             \
            const int row_ = idx_ >> 4;                                         \
            const int g_ = (idx_ & 15) ^ (row_ & 7);                            \
            GLLD((src0) + (size_t)row_ * DH + g_ * 4,                           \
                 &buf[b][w * 256 + j_ * 64]);                                   \
        }                                                                       \
    } while (0)

#define WAITVN(n)                                                               \
    do {                                                                        \
        asm volatile("s_waitcnt vmcnt(" #n ")" ::: "memory");                   \
        __builtin_amdgcn_sched_barrier(0);                                      \
    } while (0)

// ---------------- K1: content scores Q@K^T * scale -> P (zeros above diag).
// 1-D grid: qt = bid>>6 (high bits), bh = bid&63 -> resident sets span sizes.
__global__ __launch_bounds__(256, 4) void k_scores(const float* __restrict__ qp,
                                                   const float* __restrict__ kp,
                                                   float* __restrict__ P) {
    __shared__ float4 buf[2][1024];
    const int bid = blockIdx.x;
    const int qt = bid >> 6;
    const int bh = bid & 63;
    const int tid = threadIdx.x;
    const int w = tid >> 6, l = tid & 63;
    const int lm = l & 15, lg = l >> 4;
    const int q0 = qt * 64;

    Frag2 qh0[4], qh1[4];  // pre-scaled by SCALE
#pragma unroll
    for (int nt = 0; nt < 4; ++nt) {
        const float* qrow = qp + ((size_t)bh * SQ + q0 + nt * 16 + lm) * DH + lg * 8;
        qh0[nt] = load_split(qrow, SCALE);
        qh1[nt] = load_split(qrow + 32, SCALE);
    }
    const float* kb = kp + (size_t)bh * SK * DH;
    const int nt_ = qt + 1;

    STAGE64(kb, 0);
#pragma unroll 1
    for (int t = 0; t < nt_; ++t) {
        if (t + 1 < nt_) {
            STAGE64(kb + (size_t)(t + 1) * 64 * DH, (t + 1) & 1);
            WAITVN(4);  // stage(t)+stores(t-1) landed; stage(t+1) in flight
        } else {
            WAITVN(0);
        }
        const float4* L = buf[t & 1];
        const int R = w * 16 + lm;
        const int sw = R & 7;
        float4 f0 = L[R * 16 + ((2 * lg) ^ sw)];
        float4 f1 = L[R * 16 + ((2 * lg + 1) ^ sw)];
        float4 f2 = L[R * 16 + ((8 + 2 * lg) ^ sw)];
        float4 f3 = L[R * 16 + ((9 + 2 * lg) ^ sw)];
        bf16x8 alo = pack_bf8(f0, f1);
        bf16x8 ahi = pack_bf8(f2, f3);
        const int kq = t * 64 + w * 16 + lg * 4;
        const bool diag = (t == qt);
#pragma unroll
        for (int nt = 0; nt < 4; ++nt) {
            f32x4 acc = {0.f, 0.f, 0.f, 0.f};
            acc = MFMA(alo, qh0[nt].h, acc);
            acc = MFMA(alo, qh0[nt].l, acc);
            acc = MFMA(ahi, qh1[nt].h, acc);
            acc = MFMA(ahi, qh1[nt].l, acc);
            const int qe = q0 + nt * 16 + lm;
            float ov[4];
#pragma unroll
            for (int r = 0; r < 4; ++r)
                ov[r] = (!diag || (kq + r <= qe)) ? acc[r] : 0.f;
            float4 o;
            o.x = ov[0]; o.y = ov[1]; o.z = ov[2]; o.w = ov[3];
            *reinterpret_cast<float4*>(&P[((size_t)bh * SQ + qe) * SK + kq]) = o;
        }
    }
    // zero-fill tiles fully above the diagonal
    const float4 z = {0.f, 0.f, 0.f, 0.f};
#pragma unroll 1
    for (int t = nt_; t < 16; ++t) {
        const int kq = t * 64 + w * 16 + lg * 4;
#pragma unroll
        for (int nt = 0; nt < 4; ++nt) {
            const int qe = q0 + nt * 16 + lm;
            *reinterpret_cast<float4*>(&P[((size_t)bh * SQ + qe) * SK + kq]) = z;
        }
    }
}

// ---------------- K2: rel+exp -> e to P, fused PR: out = (Σ e·bigr_v)/rowsum.
// 4-stripe balanced q map: per-CU resident work sum constant (round-robin).
__global__ __launch_bounds__(256) void k_rel_pv(const float* __restrict__ query,
                                                const float* __restrict__ bigr_k,
                                                const float* __restrict__ bigr_v,
                                                float* __restrict__ P,
                                                float* __restrict__ out,
                                                float* __restrict__ rs) {
    __shared__ float4 buf[2][1024];  // staging; reused for pr cross-wave reduce
    __shared__ float red[4][64];
    __shared__ float rsum[64];
    int q;
    {
        const int bid = blockIdx.x, c = bid & 255;
        switch (bid >> 8) {
            case 0:  q = 1023 - c; break;
            case 1:  q = c;        break;
            case 2:  q = 767 - c;  break;
            default: q = 256 + c;  break;
        }
    }
    const int KE = q + 1;
    const int nt_ = (KE + 63) >> 6;
    const int tid = threadIdx.x;
    const int w = tid >> 6, l = tid & 63;
    const int lm = l & 15, lg = l >> 4;

    Frag2 qh0[4], qh1[4];  // pre-scaled
    float* prow[4];
#pragma unroll
    for (int nt = 0; nt < 4; ++nt) {
        const int bh = nt * 16 + lm;
        const float* qrow = query + ((size_t)bh * SQ + q) * DH + lg * 8;
        qh0[nt] = load_split(qrow, SCALE);
        qh1[nt] = load_split(qrow + 32, SCALE);
        prow[nt] = P + ((size_t)bh * SQ + q) * SK;
    }
    const float* bk = bigr_k + (size_t)q * SK * DH;
    const float* bv = bigr_v + (size_t)q * SK * DH;
    float lsum[4] = {0.f, 0.f, 0.f, 0.f};
    f32x4 pr[4][4];  // [nt(bh group)][ntd(d group)]
#pragma unroll
    for (int a = 0; a < 4; ++a)
#pragma unroll
        for (int b = 0; b < 4; ++b) pr[a][b] = (f32x4){0.f, 0.f, 0.f, 0.f};

    STAGE64(bk, 0);
#pragma unroll 1
    for (int t = 0; t < nt_; ++t) {
        const int kq = t * 64 + w * 16 + lg * 4;
        float4 pc[4];
#pragma unroll
        for (int nt = 0; nt < 4; ++nt)
            pc[nt] = *reinterpret_cast<const float4*>(prow[nt] + kq);
        // bigr_v B-fragments for this wave's 16-k stripe (consumed this iter)
        bf16x8 bvf[4];
        {
            const int kbw = t * 64 + w * 16 + 4 * lg;
#pragma unroll
            for (int ntd = 0; ntd < 4; ++ntd) {
                ushort8 u;
#pragma unroll
                for (int j = 0; j < 4; ++j)
                    u[j] = f2bf(bv[(size_t)(kbw + j) * DH + ntd * 16 + lm]);
                u[4] = 0; u[5] = 0; u[6] = 0; u[7] = 0;
                bvf[ntd] = __builtin_bit_cast(bf16x8, u);
            }
        }
        if (t + 1 < nt_) {
            STAGE64(bk + (size_t)(t + 1) * 64 * DH, (t + 1) & 1);
            WAITVN(4);  // stage(t)+pc+bv landed; stage(t+1) in flight
        } else {
            WAITVN(0);
        }
        const float4* L = buf[t & 1];
        const int R = w * 16 + lm;
        const int sw = R & 7;
        float4 f0 = L[R * 16 + ((2 * lg) ^ sw)];
        float4 f1 = L[R * 16 + ((2 * lg + 1) ^ sw)];
        float4 f2 = L[R * 16 + ((8 + 2 * lg) ^ sw)];
        float4 f3 = L[R * 16 + ((9 + 2 * lg) ^ sw)];
        bf16x8 alo = pack_bf8(f0, f1);
        bf16x8 ahi = pack_bf8(f2, f3);
#pragma unroll
        for (int nt = 0; nt < 4; ++nt) {
            f32x4 acc = {0.f, 0.f, 0.f, 0.f};
            acc = MFMA(alo, qh0[nt].h, acc);
            acc = MFMA(alo, qh0[nt].l, acc);
            acc = MFMA(ahi, qh1[nt].h, acc);
            acc = MFMA(ahi, qh1[nt].l, acc);
            const float4 c = pc[nt];
            float cv[4] = {c.x, c.y, c.z, c.w};
            float ov[4];
#pragma unroll
            for (int r = 0; r < 4; ++r) {
                float e = (kq + r < KE) ? __expf(cv[r] + acc[r]) : 0.f;
                ov[r] = e;
                lsum[nt] += e;
            }
            float4 o;
            o.x = ov[0]; o.y = ov[1]; o.z = ov[2]; o.w = ov[3];
            *reinterpret_cast<float4*>(prow[nt] + kq) = o;
            // PR accumulate: A = e (this lane's quad in slots 0..3), K=16 via
            // zeroed upper half; D[m=bh_in=lg*4+r][n=d_in=lm].
            ushort8 ua;
#pragma unroll
            for (int j = 0; j < 4; ++j) ua[j] = f2bf(ov[j]);
            ua[4] = 0; ua[5] = 0; ua[6] = 0; ua[7] = 0;
            bf16x8 af = __builtin_bit_cast(bf16x8, ua);
#pragma unroll
            for (int ntd = 0; ntd < 4; ++ntd)
                pr[nt][ntd] = MFMA(af, bvf[ntd], pr[nt][ntd]);
        }
    }

    // ---- row-sum reduce -> rsum (recip) in LDS + rs in global ----
#pragma unroll
    for (int nt = 0; nt < 4; ++nt) {
        float v = lsum[nt];
        v += __shfl_xor(v, 16);
        v += __shfl_xor(v, 32);
        if (l < 16) red[w][nt * 16 + l] = v;
    }
    __syncthreads();  // red ready; also: all staging reads of buf complete
    if (tid < 64) {
        float nr = 1.0f / (red[0][tid] + red[1][tid] + red[2][tid] + red[3][tid]);
        rsum[tid] = nr;
        rs[(size_t)q * 64 + tid] = nr;
    }
    // ---- pr cross-wave reduce in buf (32 KB = 2 halves of 4096 floats) ----
    float* prbuf = reinterpret_cast<float*>(&buf[0][0]);
    if (w < 2) {
        float* dst = prbuf + w * 4096;
#pragma unroll
        for (int nt = 0; nt < 4; ++nt)
#pragma unroll
            for (int ntd = 0; ntd < 4; ++ntd)
#pragma unroll
                for (int r = 0; r < 4; ++r)
                    dst[(nt * 16 + lg * 4 + r) * 64 + ntd * 16 + lm] = pr[nt][ntd][r];
    }
    __syncthreads();  // halves written (w0,w1); rsum ready
    if (w >= 2) {
        float* dst = prbuf + (w - 2) * 4096;
#pragma unroll
        for (int nt = 0; nt < 4; ++nt)
#pragma unroll
            for (int ntd = 0; ntd < 4; ++ntd)
#pragma unroll
                for (int r = 0; r < 4; ++r)
                    dst[(nt * 16 + lg * 4 + r) * 64 + ntd * 16 + lm] += pr[nt][ntd][r];
    }
    __syncthreads();
    // ---- final: out[bh][q][d] = (half0 + half1) * rsum[bh] ----
#pragma unroll
    for (int i = 0; i < 4; ++i) {
        const int f4i = tid + i * 256;  // 0..1023 float4s
        float4 a = reinterpret_cast<const float4*>(prbuf)[f4i];
        float4 b = reinterpret_cast<const float4*>(prbuf)[1024 + f4i];
        const int fl = f4i * 4;
        const int bh = fl >> 6, d = fl & 63;
        const float nr = rsum[bh];
        float4 o = {(a.x + b.x) * nr, (a.y + b.y) * nr,
                    (a.z + b.z) * nr, (a.w + b.w) * nr};
        *reinterpret_cast<float4*>(&out[((size_t)bh * SQ + q) * DH + d]) = o;
    }
}

// ---------------- K3: Pn = e*recip written in place (final p_attn);
// out += Pn @ V. 1-D grid: qt = bid>>6, bh = bid&63 (balanced residency).
__global__ __launch_bounds__(256) void k_pv(float* __restrict__ P,
                                            const float* __restrict__ V,
                                            const float* __restrict__ rs,
                                            float* __restrict__ out) {
    const int bid = blockIdx.x;
    const int qt = bid >> 6;
    const int bh = bid & 63;
    const int tid = threadIdx.x;
    const int w = tid >> 6, l = tid & 63;
    const int lm = l & 15, lg = l >> 4;
    const int q0 = qt * 64 + w * 16;

    const float wrecip = rs[(size_t)(q0 + lm) * 64 + bh];
    float orecip[4];
#pragma unroll
    for (int r = 0; r < 4; ++r)
        orecip[r] = rs[(size_t)(q0 + lg * 4 + r) * 64 + bh];

    f32x4 acc[4] = {{0.f,0.f,0.f,0.f},{0.f,0.f,0.f,0.f},{0.f,0.f,0.f,0.f},{0.f,0.f,0.f,0.f}};
    const int kend = q0 + 16;
    for (int k0 = 0; k0 < kend; k0 += 32) {
        float* arow = P + ((size_t)bh * SQ + q0 + lm) * SK + k0 + lg * 8;
        float4 x0 = *reinterpret_cast<const float4*>(arow);
        float4 x1 = *reinterpret_cast<const float4*>(arow + 4);
        float4 y0 = {x0.x * wrecip, x0.y * wrecip, x0.z * wrecip, x0.w * wrecip};
        float4 y1 = {x1.x * wrecip, x1.y * wrecip, x1.z * wrecip, x1.w * wrecip};
        *reinterpret_cast<float4*>(arow) = y0;       // final normalized p_attn
        *reinterpret_cast<float4*>(arow + 4) = y1;
        bf16x8 a = pack_bf8(x0, x1);                 // unnormalized e
#pragma unroll
        for (int nt = 0; nt < 4; ++nt) {
            const float* bcol = V + ((size_t)bh * SK + k0 + lg * 8) * DH + nt * 16 + lm;
            bf16x8 b = load_bf8_strided(bcol, DH);
            acc[nt] = MFMA(a, b, acc[nt]);
        }
    }
#pragma unroll
    for (int nt = 0; nt < 4; ++nt)
#pragma unroll
        for (int r = 0; r < 4; ++r)
            out[((size_t)bh * SQ + q0 + lg * 4 + r) * DH + nt * 16 + lm] +=
                acc[nt][r] * orecip[r];
}

extern "C" void kernel_launch(void* const* d_in, const int* in_sizes, int n_in,
                              void* d_out, int out_size, void* d_ws, size_t ws_size,
                              hipStream_t stream) {
    const float* query  = (const float*)d_in[0];
    const float* key    = (const float*)d_in[1];
    const float* value  = (const float*)d_in[2];
    const float* bigr_k = (const float*)d_in[3];
    const float* bigr_v = (const float*)d_in[4];
    float* out = (float*)d_out;                       // BH*SQ*DH
    float* P   = out + (size_t)BH * SQ * DH;          // BH*SQ*SK
    float* rs  = (float*)d_ws;                        // [SQ][BH] recip = 256 KB

    k_scores<<<dim3(1024), 256, 0, stream>>>(query, key, P);
    k_rel_pv<<<dim3(SQ), 256, 0, stream>>>(query, bigr_k, bigr_v, P, out, rs);
    k_pv<<<dim3(1024), 256, 0, stream>>>(P, value, rs, out);
}

// Round 20
// 406.116 us; speedup vs baseline: 1.0691x; 1.0012x over previous
//
#include <hip/hip_runtime.h>
#include <hip/hip_bf16.h>

// Relative-position causal attention, B=4 H=16 Q=K=1024 D=64 (fp32 in/out).
// d_out = [output (BH*Q*D) | p_attn (BH*Q*K)] fp32.
// K1 k_scores: content scores (LDS-staged GEMM, counted vmcnt, 1-D grid).
// K2 k_rel_pv: PAIRED-q blocks (grid 512): block c handles q=1023-c then q=c
//              -> uniform ~17 tiles/block, no residency decay, same total
//              per-row fixed cost as 1024 blocks. Inner body identical to R16.
// K3 k_pv: Pn = e*recip in place (final p_attn), out += Pn@V (1-D grid).

#define BH 64
#define SQ 1024
#define SK 1024
#define DH 64
#define SCALE 0.125f

typedef __attribute__((ext_vector_type(4))) float f32x4;
typedef __attribute__((ext_vector_type(8))) unsigned short ushort8;
typedef __attribute__((ext_vector_type(8))) __bf16 bf16x8;

static __device__ inline unsigned short f2bf(float x) {
    unsigned u = __float_as_uint(x);
    unsigned r = u + 0x7FFFu + ((u >> 16) & 1u);
    return (unsigned short)(r >> 16);
}
static __device__ inline float bf2f(unsigned short s) {
    return __uint_as_float(((unsigned)s) << 16);
}

struct Frag2 { bf16x8 h, l; };

// Load 8 fp32, scale, split into hi/lo bf16 fragments (hi+lo == scaled value).
static __device__ inline Frag2 load_split(const float* __restrict__ p, float scale) {
    float4 x0 = *reinterpret_cast<const float4*>(p);
    float4 x1 = *reinterpret_cast<const float4*>(p + 4);
    float v[8] = {x0.x, x0.y, x0.z, x0.w, x1.x, x1.y, x1.z, x1.w};
    ushort8 uh, ul;
#pragma unroll
    for (int j = 0; j < 8; ++j) {
        float s = v[j] * scale;
        unsigned short h = f2bf(s);
        float r = s - bf2f(h);
        uh[j] = h;
        ul[j] = f2bf(r);
    }
    Frag2 f;
    f.h = __builtin_bit_cast(bf16x8, uh);
    f.l = __builtin_bit_cast(bf16x8, ul);
    return f;
}

static __device__ inline bf16x8 pack_bf8(float4 x0, float4 x1) {
    float v[8] = {x0.x, x0.y, x0.z, x0.w, x1.x, x1.y, x1.z, x1.w};
    ushort8 u;
#pragma unroll
    for (int j = 0; j < 8; ++j) u[j] = f2bf(v[j]);
    return __builtin_bit_cast(bf16x8, u);
}

static __device__ inline bf16x8 load_bf8(const float* __restrict__ p) {
    float4 x0 = *reinterpret_cast<const float4*>(p);
    float4 x1 = *reinterpret_cast<const float4*>(p + 4);
    return pack_bf8(x0, x1);
}

static __device__ inline bf16x8 load_bf8_strided(const float* __restrict__ p, int stride) {
    ushort8 u;
#pragma unroll
    for (int j = 0; j < 8; ++j) u[j] = f2bf(p[(size_t)j * stride]);
    return __builtin_bit_cast(bf16x8, u);
}

#define MFMA(a, b, c) __builtin_amdgcn_mfma_f32_16x16x32_bf16((a), (b), (c), 0, 0, 0)

// async global -> LDS, 16B per lane; lds dest is wave-uniform base + lane*16
#define GLLD(g, s)                                                              \
    __builtin_amdgcn_global_load_lds(                                           \
        (const __attribute__((address_space(1))) void*)(g),                     \
        (__attribute__((address_space(3))) void*)(s), 16, 0, 0)

// stage a 64x64 fp32 tile (rows at src0 + row*DH) into buf[b]; WAVE-PRIVATE:
// wave w stages rows [w*16, w*16+16) and later reads only those rows.
// source pre-swizzled (chunk ^= row&7) so linear LDS + swizzled reads match.
#define STAGE64(src0, b)                                                        \
    do {                                                                        \
        _Pragma("unroll")                                                       \
        for (int j_ = 0; j_ < 4; ++j_) {                                        \
            const int idx_ = w * 256 + j_ * 64 + l;                             \
            const int row_ = idx_ >> 4;                                         \
            const int g_ = (idx_ & 15) ^ (row_ & 7);                            \
            GLLD((src0) + (size_t)row_ * DH + g_ * 4,                           \
                 &buf[b][w * 256 + j_ * 64]);                                   \
        }                                                                       \
    } while (0)

#define WAITVN(n)                                                               \
    do {                                                                        \
        asm volatile("s_waitcnt vmcnt(" #n ")" ::: "memory");                   \
        __builtin_amdgcn_sched_barrier(0);                                      \
    } while (0)

// ---------------- K1: content scores Q@K^T * scale -> P (zeros above diag).
// 1-D grid: qt = bid>>6 (high bits), bh = bid&63 -> resident sets span sizes.
__global__ __launch_bounds__(256, 4) void k_scores(const float* __restrict__ qp,
                                                   const float* __restrict__ kp,
                                                   float* __restrict__ P) {
    __shared__ float4 buf[2][1024];
    const int bid = blockIdx.x;
    const int qt = bid >> 6;
    const int bh = bid & 63;
    const int tid = threadIdx.x;
    const int w = tid >> 6, l = tid & 63;
    const int lm = l & 15, lg = l >> 4;
    const int q0 = qt * 64;

    Frag2 qh0[4], qh1[4];  // pre-scaled by SCALE
#pragma unroll
    for (int nt = 0; nt < 4; ++nt) {
        const float* qrow = qp + ((size_t)bh * SQ + q0 + nt * 16 + lm) * DH + lg * 8;
        qh0[nt] = load_split(qrow, SCALE);
        qh1[nt] = load_split(qrow + 32, SCALE);
    }
    const float* kb = kp + (size_t)bh * SK * DH;
    const int nt_ = qt + 1;

    STAGE64(kb, 0);
#pragma unroll 1
    for (int t = 0; t < nt_; ++t) {
        if (t + 1 < nt_) {
            STAGE64(kb + (size_t)(t + 1) * 64 * DH, (t + 1) & 1);
            WAITVN(4);  // stage(t)+stores(t-1) landed; stage(t+1) in flight
        } else {
            WAITVN(0);
        }
        const float4* L = buf[t & 1];
        const int R = w * 16 + lm;
        const int sw = R & 7;
        float4 f0 = L[R * 16 + ((2 * lg) ^ sw)];
        float4 f1 = L[R * 16 + ((2 * lg + 1) ^ sw)];
        float4 f2 = L[R * 16 + ((8 + 2 * lg) ^ sw)];
        float4 f3 = L[R * 16 + ((9 + 2 * lg) ^ sw)];
        bf16x8 alo = pack_bf8(f0, f1);
        bf16x8 ahi = pack_bf8(f2, f3);
        const int kq = t * 64 + w * 16 + lg * 4;
        const bool diag = (t == qt);
#pragma unroll
        for (int nt = 0; nt < 4; ++nt) {
            f32x4 acc = {0.f, 0.f, 0.f, 0.f};
            acc = MFMA(alo, qh0[nt].h, acc);
            acc = MFMA(alo, qh0[nt].l, acc);
            acc = MFMA(ahi, qh1[nt].h, acc);
            acc = MFMA(ahi, qh1[nt].l, acc);
            const int qe = q0 + nt * 16 + lm;
            float ov[4];
#pragma unroll
            for (int r = 0; r < 4; ++r)
                ov[r] = (!diag || (kq + r <= qe)) ? acc[r] : 0.f;
            float4 o;
            o.x = ov[0]; o.y = ov[1]; o.z = ov[2]; o.w = ov[3];
            *reinterpret_cast<float4*>(&P[((size_t)bh * SQ + qe) * SK + kq]) = o;
        }
    }
    // zero-fill tiles fully above the diagonal
    const float4 z = {0.f, 0.f, 0.f, 0.f};
#pragma unroll 1
    for (int t = nt_; t < 16; ++t) {
        const int kq = t * 64 + w * 16 + lg * 4;
#pragma unroll
        for (int nt = 0; nt < 4; ++nt) {
            const int qe = q0 + nt * 16 + lm;
            *reinterpret_cast<float4*>(&P[((size_t)bh * SQ + qe) * SK + kq]) = z;
        }
    }
}

// ---------------- K2: rel+exp -> e to P, fused PR: out = (Σ e·bigr_v)/rowsum.
// PAIRED-q: block c processes q=1023-c then q=c (uniform ~17 tiles/block).
__global__ __launch_bounds__(256) void k_rel_pv(const float* __restrict__ query,
                                                const float* __restrict__ bigr_k,
                                                const float* __restrict__ bigr_v,
                                                float* __restrict__ P,
                                                float* __restrict__ out,
                                                float* __restrict__ rs) {
    __shared__ float4 buf[2][1024];  // staging; reused for pr cross-wave reduce
    __shared__ float red[4][64];
    __shared__ float rsum[64];
    const int bid = blockIdx.x;
    const int tid = threadIdx.x;
    const int w = tid >> 6, l = tid & 63;
    const int lm = l & 15, lg = l >> 4;

#pragma unroll 1
    for (int hh = 0; hh < 2; ++hh) {
        const int q = hh ? bid : (SQ - 1 - bid);  // big row first
        const int KE = q + 1;
        const int nt_ = (KE + 63) >> 6;

        Frag2 qh0[4], qh1[4];  // pre-scaled
        float* prow[4];
#pragma unroll
        for (int nt = 0; nt < 4; ++nt) {
            const int bh = nt * 16 + lm;
            const float* qrow = query + ((size_t)bh * SQ + q) * DH + lg * 8;
            qh0[nt] = load_split(qrow, SCALE);
            qh1[nt] = load_split(qrow + 32, SCALE);
            prow[nt] = P + ((size_t)bh * SQ + q) * SK;
        }
        const float* bk = bigr_k + (size_t)q * SK * DH;
        const float* bv = bigr_v + (size_t)q * SK * DH;
        float lsum[4] = {0.f, 0.f, 0.f, 0.f};
        f32x4 pr[4][4];  // [nt(bh group)][ntd(d group)]
#pragma unroll
        for (int a = 0; a < 4; ++a)
#pragma unroll
            for (int b = 0; b < 4; ++b) pr[a][b] = (f32x4){0.f, 0.f, 0.f, 0.f};

        STAGE64(bk, 0);
#pragma unroll 1
        for (int t = 0; t < nt_; ++t) {
            const int kq = t * 64 + w * 16 + lg * 4;
            float4 pc[4];
#pragma unroll
            for (int nt = 0; nt < 4; ++nt)
                pc[nt] = *reinterpret_cast<const float4*>(prow[nt] + kq);
            // bigr_v B-fragments for this wave's 16-k stripe (consumed this iter)
            bf16x8 bvf[4];
            {
                const int kbw = t * 64 + w * 16 + 4 * lg;
#pragma unroll
                for (int ntd = 0; ntd < 4; ++ntd) {
                    ushort8 u;
#pragma unroll
                    for (int j = 0; j < 4; ++j)
                        u[j] = f2bf(bv[(size_t)(kbw + j) * DH + ntd * 16 + lm]);
                    u[4] = 0; u[5] = 0; u[6] = 0; u[7] = 0;
                    bvf[ntd] = __builtin_bit_cast(bf16x8, u);
                }
            }
            if (t + 1 < nt_) {
                STAGE64(bk + (size_t)(t + 1) * 64 * DH, (t + 1) & 1);
                WAITVN(4);  // stage(t)+pc+bv landed; stage(t+1) in flight
            } else {
                WAITVN(0);
            }
            const float4* L = buf[t & 1];
            const int R = w * 16 + lm;
            const int sw = R & 7;
            float4 f0 = L[R * 16 + ((2 * lg) ^ sw)];
            float4 f1 = L[R * 16 + ((2 * lg + 1) ^ sw)];
            float4 f2 = L[R * 16 + ((8 + 2 * lg) ^ sw)];
            float4 f3 = L[R * 16 + ((9 + 2 * lg) ^ sw)];
            bf16x8 alo = pack_bf8(f0, f1);
            bf16x8 ahi = pack_bf8(f2, f3);
#pragma unroll
            for (int nt = 0; nt < 4; ++nt) {
                f32x4 acc = {0.f, 0.f, 0.f, 0.f};
                acc = MFMA(alo, qh0[nt].h, acc);
                acc = MFMA(alo, qh0[nt].l, acc);
                acc = MFMA(ahi, qh1[nt].h, acc);
                acc = MFMA(ahi, qh1[nt].l, acc);
                const float4 c = pc[nt];
                float cv[4] = {c.x, c.y, c.z, c.w};
                float ov[4];
#pragma unroll
                for (int r = 0; r < 4; ++r) {
                    float e = (kq + r < KE) ? __expf(cv[r] + acc[r]) : 0.f;
                    ov[r] = e;
                    lsum[nt] += e;
                }
                float4 o;
                o.x = ov[0]; o.y = ov[1]; o.z = ov[2]; o.w = ov[3];
                *reinterpret_cast<float4*>(prow[nt] + kq) = o;
                // PR accumulate: A = e quad in slots 0..3, K=16 (upper half zero)
                ushort8 ua;
#pragma unroll
                for (int j = 0; j < 4; ++j) ua[j] = f2bf(ov[j]);
                ua[4] = 0; ua[5] = 0; ua[6] = 0; ua[7] = 0;
                bf16x8 af = __builtin_bit_cast(bf16x8, ua);
#pragma unroll
                for (int ntd = 0; ntd < 4; ++ntd)
                    pr[nt][ntd] = MFMA(af, bvf[ntd], pr[nt][ntd]);
            }
        }

        // ---- row-sum reduce -> rsum (recip) in LDS + rs in global ----
#pragma unroll
        for (int nt = 0; nt < 4; ++nt) {
            float v = lsum[nt];
            v += __shfl_xor(v, 16);
            v += __shfl_xor(v, 32);
            if (l < 16) red[w][nt * 16 + l] = v;
        }
        __syncthreads();  // red ready; all staging reads of buf complete
        if (tid < 64) {
            float nr = 1.0f / (red[0][tid] + red[1][tid] + red[2][tid] + red[3][tid]);
            rsum[tid] = nr;
            rs[(size_t)q * 64 + tid] = nr;
        }
        // ---- pr cross-wave reduce in buf (32 KB = 2 halves of 4096 floats) ----
        float* prbuf = reinterpret_cast<float*>(&buf[0][0]);
        if (w < 2) {
            float* dst = prbuf + w * 4096;
#pragma unroll
            for (int nt = 0; nt < 4; ++nt)
#pragma unroll
                for (int ntd = 0; ntd < 4; ++ntd)
#pragma unroll
                    for (int r = 0; r < 4; ++r)
                        dst[(nt * 16 + lg * 4 + r) * 64 + ntd * 16 + lm] = pr[nt][ntd][r];
        }
        __syncthreads();  // halves written (w0,w1); rsum ready
        if (w >= 2) {
            float* dst = prbuf + (w - 2) * 4096;
#pragma unroll
            for (int nt = 0; nt < 4; ++nt)
#pragma unroll
                for (int ntd = 0; ntd < 4; ++ntd)
#pragma unroll
                    for (int r = 0; r < 4; ++r)
                        dst[(nt * 16 + lg * 4 + r) * 64 + ntd * 16 + lm] += pr[nt][ntd][r];
        }
        __syncthreads();
        // ---- final: out[bh][q][d] = (half0 + half1) * rsum[bh] ----
#pragma unroll
        for (int i = 0; i < 4; ++i) {
            const int f4i = tid + i * 256;  // 0..1023 float4s
            float4 a = reinterpret_cast<const float4*>(prbuf)[f4i];
            float4 b = reinterpret_cast<const float4*>(prbuf)[1024 + f4i];
            const int fl = f4i * 4;
            const int bh = fl >> 6, d = fl & 63;
            const float nr = rsum[bh];
            float4 o = {(a.x + b.x) * nr, (a.y + b.y) * nr,
                        (a.z + b.z) * nr, (a.w + b.w) * nr};
            *reinterpret_cast<float4*>(&out[((size_t)bh * SQ + q) * DH + d]) = o;
        }
        __syncthreads();  // prbuf reads done before next half re-stages buf
    }
}

// ---------------- K3: Pn = e*recip written in place (final p_attn);
// out += Pn @ V. 1-D grid: qt = bid>>6, bh = bid&63 (balanced residency).
__global__ __launch_bounds__(256) void k_pv(float* __restrict__ P,
                                            const float* __restrict__ V,
                                            const float* __restrict__ rs,
                                            float* __restrict__ out) {
    const int bid = blockIdx.x;
    const int qt = bid >> 6;
    const int bh = bid & 63;
    const int tid = threadIdx.x;
    const int w = tid >> 6, l = tid & 63;
    const int lm = l & 15, lg = l >> 4;
    const int q0 = qt * 64 + w * 16;

    const float wrecip = rs[(size_t)(q0 + lm) * 64 + bh];
    float orecip[4];
#pragma unroll
    for (int r = 0; r < 4; ++r)
        orecip[r] = rs[(size_t)(q0 + lg * 4 + r) * 64 + bh];

    f32x4 acc[4] = {{0.f,0.f,0.f,0.f},{0.f,0.f,0.f,0.f},{0.f,0.f,0.f,0.f},{0.f,0.f,0.f,0.f}};
    const int kend = q0 + 16;
    for (int k0 = 0; k0 < kend; k0 += 32) {
        float* arow = P + ((size_t)bh * SQ + q0 + lm) * SK + k0 + lg * 8;
        float4 x0 = *reinterpret_cast<const float4*>(arow);
        float4 x1 = *reinterpret_cast<const float4*>(arow + 4);
        float4 y0 = {x0.x * wrecip, x0.y * wrecip, x0.z * wrecip, x0.w * wrecip};
        float4 y1 = {x1.x * wrecip, x1.y * wrecip, x1.z * wrecip, x1.w * wrecip};
        *reinterpret_cast<float4*>(arow) = y0;       // final normalized p_attn
        *reinterpret_cast<float4*>(arow + 4) = y1;
        bf16x8 a = pack_bf8(x0, x1);                 // unnormalized e
#pragma unroll
        for (int nt = 0; nt < 4; ++nt) {
            const float* bcol = V + ((size_t)bh * SK + k0 + lg * 8) * DH + nt * 16 + lm;
            bf16x8 b = load_bf8_strided(bcol, DH);
            acc[nt] = MFMA(a, b, acc[nt]);
        }
    }
#pragma unroll
    for (int nt = 0; nt < 4; ++nt)
#pragma unroll
        for (int r = 0; r < 4; ++r)
            out[((size_t)bh * SQ + q0 + lg * 4 + r) * DH + nt * 16 + lm] +=
                acc[nt][r] * orecip[r];
}

extern "C" void kernel_launch(void* const* d_in, const int* in_sizes, int n_in,
                              void* d_out, int out_size, void* d_ws, size_t ws_size,
                              hipStream_t stream) {
    const float* query  = (const float*)d_in[0];
    const float* key    = (const float*)d_in[1];
    const float* value  = (const float*)d_in[2];
    const float* bigr_k = (const float*)d_in[3];
    const float* bigr_v = (const float*)d_in[4];
    float* out = (float*)d_out;                       // BH*SQ*DH
    float* P   = out + (size_t)BH * SQ * DH;          // BH*SQ*SK
    float* rs  = (float*)d_ws;                        // [SQ][BH] recip = 256 KB

    k_scores<<<dim3(1024), 256, 0, stream>>>(query, key, P);
    k_rel_pv<<<dim3(SQ / 2), 256, 0, stream>>>(query, bigr_k, bigr_v, P, out, rs);
    k_pv<<<dim3(1024), 256, 0, stream>>>(P, value, rs, out);
}